// Round 1
// baseline (166.181 us; speedup 1.0000x reference)
//
#include <hip/hip_runtime.h>
#include <stdint.h>

// Problem constants (fixed by reference)
#define B_  32
#define N_  128
#define NIN 16
#define K_  4
#define E_  (N_*(N_-1))   // 16256

typedef float f4   __attribute__((ext_vector_type(4)));
typedef short bf8  __attribute__((ext_vector_type(8)));   // 8 bf16 bit-patterns

static __device__ __forceinline__ unsigned short f2bf(float f) {
    union { float f; unsigned u; } v; v.f = f;
    unsigned r = v.u + 0x7FFFu + ((v.u >> 16) & 1u);   // RNE
    return (unsigned short)(r >> 16);
}
static __device__ __forceinline__ float bf2f(unsigned short h) {
    union { unsigned u; float f; } v; v.u = ((unsigned)h) << 16;
    return v.f;
}

// ---------------------------------------------------------------------------
// P1: per-node layer-1 halves.  S[k][b][n][c] = sum_f x[b][n][f]*W1[k][f][c]
//     R[k][b][n][c] = sum_f x[b][n][f]*W1[k][16+f][c] + b1[k][c]
// Stored bf16.  gid bits: c:6 | n:7 | b:5 | k:2  (matches ((k*B+b)*N+n)*64+c)
// ---------------------------------------------------------------------------
__global__ __launch_bounds__(256) void precompute_sr(
    const float* __restrict__ inp, const float* __restrict__ W1,
    const float* __restrict__ b1,
    unsigned short* __restrict__ Sb, unsigned short* __restrict__ Rb)
{
    int gid = blockIdx.x * 256 + threadIdx.x;       // 1<<20 total
    int c = gid & 63;
    int n = (gid >> 6) & 127;
    int b = (gid >> 13) & 31;
    int k = gid >> 18;
    float s = 0.f, r = 0.f;
    const float* w1s = W1 + (k*32)*64 + c;
    const float* w1r = W1 + (k*32 + 16)*64 + c;
    const float* xp  = inp + (b*NIN)*N_ + n;        // inputs[b][f][n]
    #pragma unroll
    for (int f = 0; f < 16; ++f) {
        float xv = xp[f*N_];
        s += xv * w1s[f*64];
        r += xv * w1r[f*64];
    }
    r += b1[k*64 + c];
    Sb[gid] = f2bf(s);
    Rb[gid] = f2bf(r);
}

// ---------------------------------------------------------------------------
// P2: pack W2 into B-operand fragment layout for mfma_f32_16x16x32_bf16:
//     lane holds B[kk = quad*8 + i][n = lane&15], frag index (k, ks, nt)
// ---------------------------------------------------------------------------
__global__ __launch_bounds__(256) void pack_w2(
    const float* __restrict__ W2, unsigned short* __restrict__ w2b)
{
    int t = blockIdx.x * 256 + threadIdx.x;         // 16384 total
    int i    = t & 7;
    int lane = (t >> 3) & 63;
    int nt   = (t >> 9) & 3;
    int ks   = (t >> 11) & 1;
    int k    = t >> 12;
    int c = ks*32 + (lane >> 4)*8 + i;
    int o = nt*16 + (lane & 15);
    w2b[t] = f2bf(W2[(k*64 + c)*64 + o]);
}

// ---------------------------------------------------------------------------
// Edge MLP (MFMA) + receiver aggregation + node MLP, fused.
// One block per (b, r); wave k handles edge type k over 127 edges (pad to 128).
// ---------------------------------------------------------------------------
__global__ __launch_bounds__(256) void edge_node(
    const unsigned short* __restrict__ Sb,
    const unsigned short* __restrict__ Rb,
    const unsigned short* __restrict__ w2b,
    const float* __restrict__ inp,
    const float* __restrict__ rt,
    const float* __restrict__ b2,
    const float* __restrict__ Wo1, const float* __restrict__ bo1,
    const float* __restrict__ Wo2, const float* __restrict__ bo2,
    const float* __restrict__ Wo3, const float* __restrict__ bo3,
    float* __restrict__ out)
{
    __shared__ float aggK[4*64];
    __shared__ float aug[80];
    __shared__ float h1s[64];
    __shared__ float h2s[64];

    const int tid  = threadIdx.x;
    const int r    = blockIdx.x & 127;
    const int b    = blockIdx.x >> 7;
    const int k    = tid >> 6;      // wave id = edge type
    const int lane = tid & 63;
    const int col  = lane & 15;
    const int q    = lane >> 4;

    // stage x[b][r][:] for node MLP (aug[0..15])
    if (tid < 16) aug[tid] = inp[(b*NIN + tid)*N_ + r];

    // W2 B-operand fragments [ks][nt] (reused over all M-tiles)
    const bf8* w2v = (const bf8*)w2b;
    bf8 w2f[2][4];
    #pragma unroll
    for (int ks = 0; ks < 2; ++ks)
        #pragma unroll
        for (int nt = 0; nt < 4; ++nt)
            w2f[ks][nt] = w2v[((k*2 + ks)*4 + nt)*64 + lane];

    // Receiver-side R row -> fp32 registers (reused over all edges)
    const bf8* Sv = (const bf8*)Sb;
    const bf8* Rv = (const bf8*)Rb;
    const int rowbaseR = ((k*B_ + b)*N_ + r) * 8;   // bf8 units (64 elems = 8 vecs)
    float rf[2][8];
    #pragma unroll
    for (int ks = 0; ks < 2; ++ks) {
        bf8 rv = Rv[rowbaseR + ks*4 + q];
        #pragma unroll
        for (int i = 0; i < 8; ++i) rf[ks][i] = bf2f((unsigned short)rv[i]);
    }

    float b2v[4];
    #pragma unroll
    for (int nt = 0; nt < 4; ++nt) b2v[nt] = b2[k*64 + nt*16 + col];

    float aggacc[4] = {0.f, 0.f, 0.f, 0.f};
    const int rowbaseS = (k*B_ + b)*N_*8;
    const int ebase    = b*E_ + r*127;

    for (int mt = 0; mt < 8; ++mt) {
        // --- A fragments: h1 = relu(S[sender] + R[recv]) on the fly ---
        int j = mt*16 + col;                 // A-operand row = lane&15
        int s = j + (j >= r ? 1 : 0);        // analytic one-hot decode of rel_send
        if (s > 127) s = 127;                // pad row (j==127), masked via rt=0
        bf8 h1f[2];
        #pragma unroll
        for (int ks = 0; ks < 2; ++ks) {
            bf8 sv = Sv[rowbaseS + s*8 + ks*4 + q];
            bf8 h;
            #pragma unroll
            for (int i = 0; i < 8; ++i) {
                float v = bf2f((unsigned short)sv[i]) + rf[ks][i];
                h[i] = (short)f2bf(fmaxf(v, 0.f));
            }
            h1f[ks] = h;
        }
        // --- MFMA: C[16x16] per nt, K=64 in 2 steps ---
        f4 acc[4];
        #pragma unroll
        for (int nt = 0; nt < 4; ++nt) {
            f4 z = {0.f, 0.f, 0.f, 0.f};
            acc[nt] = __builtin_amdgcn_mfma_f32_16x16x32_bf16(h1f[0], w2f[0][nt], z, 0, 0, 0);
            acc[nt] = __builtin_amdgcn_mfma_f32_16x16x32_bf16(h1f[1], w2f[1][nt], acc[nt], 0, 0, 0);
        }
        // --- weight by rel_types and reduce over this tile's edge rows ---
        // C/D layout: col = lane&15, row = q*4 + reg  [m89-verified]
        float rtv[4];
        #pragma unroll
        for (int i = 0; i < 4; ++i) {
            int jrow = mt*16 + q*4 + i;
            rtv[i] = (jrow < 127) ? rt[(ebase + jrow)*4 + k] : 0.f;
        }
        #pragma unroll
        for (int nt = 0; nt < 4; ++nt)
            #pragma unroll
            for (int i = 0; i < 4; ++i)
                aggacc[nt] += rtv[i] * fmaxf(acc[nt][i] + b2v[nt], 0.f);
    }

    // cross-quad reduction (rows live in quads), then per-k agg -> LDS
    #pragma unroll
    for (int nt = 0; nt < 4; ++nt) {
        float v = aggacc[nt];
        v += __shfl_xor(v, 16, 64);
        v += __shfl_xor(v, 32, 64);
        if (lane < 16) aggK[k*64 + nt*16 + lane] = v;
    }
    __syncthreads();

    // ---- node MLP (fp32), threads 0..63 ----
    if (tid < 64) {
        float a = aggK[tid] + aggK[64 + tid] + aggK[128 + tid] + aggK[192 + tid];
        aug[16 + tid] = a;
    }
    __syncthreads();
    if (tid < 64) {
        float accv = bo1[tid];
        #pragma unroll 8
        for (int i = 0; i < 80; ++i) accv += aug[i] * Wo1[i*64 + tid];
        h1s[tid] = fmaxf(accv, 0.f);
    }
    __syncthreads();
    if (tid < 64) {
        float accv = bo2[tid];
        #pragma unroll 8
        for (int i = 0; i < 64; ++i) accv += h1s[i] * Wo2[i*64 + tid];
        h2s[tid] = fmaxf(accv, 0.f);
    }
    __syncthreads();
    if (tid < 16) {
        float accv = bo3[tid];
        #pragma unroll 8
        for (int i = 0; i < 64; ++i) accv += h2s[i] * Wo3[i*16 + tid];
        out[(b*NIN + tid)*N_ + r] = accv;   // pred transposed: [B, n_out, N]
    }
}

// ---------------------------------------------------------------------------
extern "C" void kernel_launch(void* const* d_in, const int* in_sizes, int n_in,
                              void* d_out, int out_size, void* d_ws, size_t ws_size,
                              hipStream_t stream)
{
    const float* inp = (const float*)d_in[0];
    // d_in[1] = rel_rec, d_in[2] = rel_send: one-hot, decoded analytically, unused
    const float* rt  = (const float*)d_in[3];
    const float* W1  = (const float*)d_in[4];
    const float* b1  = (const float*)d_in[5];
    const float* W2  = (const float*)d_in[6];
    const float* b2  = (const float*)d_in[7];
    const float* Wo1 = (const float*)d_in[8];
    const float* bo1 = (const float*)d_in[9];
    const float* Wo2 = (const float*)d_in[10];
    const float* bo2 = (const float*)d_in[11];
    const float* Wo3 = (const float*)d_in[12];
    const float* bo3 = (const float*)d_in[13];

    // workspace layout (bf16): Sb 2MB | Rb 2MB | w2b 32KB  (total ~4.25MB)
    unsigned short* Sb  = (unsigned short*)d_ws;
    unsigned short* Rb  = Sb + (1u << 20);
    unsigned short* w2b = Rb + (1u << 20);

    hipLaunchKernelGGL(precompute_sr, dim3(4096), dim3(256), 0, stream,
                       inp, W1, b1, Sb, Rb);
    hipLaunchKernelGGL(pack_w2, dim3(64), dim3(256), 0, stream, W2, w2b);
    hipLaunchKernelGGL(edge_node, dim3(B_*N_), dim3(256), 0, stream,
                       Sb, Rb, w2b, inp, rt, b2,
                       Wo1, bo1, Wo2, bo2, Wo3, bo3, (float*)d_out);
}

// Round 2
// 164.700 us; speedup vs baseline: 1.0090x; 1.0090x over previous
//
#include <hip/hip_runtime.h>
#include <stdint.h>

// Problem constants (fixed by reference)
#define B_  32
#define N_  128
#define NIN 16
#define K_  4
#define E_  (N_*(N_-1))   // 16256

typedef float    f4 __attribute__((ext_vector_type(4)));
typedef _Float16 h8 __attribute__((ext_vector_type(8)));   // 8 fp16 = 4 VGPRs

// ---------------------------------------------------------------------------
// Prep (single launch, block ranges):
//   blocks [0,4096):      S/R precompute (fp16)
//   blocks [4096,4160):   W2 -> fp16 B-operand fragments
//   blocks [4160,12352):  rel_types repack -> rtp[k][b][r][j] (j padded to 128)
// ---------------------------------------------------------------------------
__global__ __launch_bounds__(256) void prep(
    const float* __restrict__ inp, const float* __restrict__ W1,
    const float* __restrict__ b1,  const float* __restrict__ W2,
    const float* __restrict__ rt,
    _Float16* __restrict__ Sh, _Float16* __restrict__ Rh,
    _Float16* __restrict__ w2h, float* __restrict__ rtp)
{
    const int bid = blockIdx.x;
    const int tid = threadIdx.x;
    if (bid < 4096) {
        // S[k][b][n][c] = x[b][n][:]@W1[k][:16][c];  R = x@W1[k][16:][c] + b1
        int gid = bid*256 + tid;            // c:6 | n:7 | b:5 | k:2
        int c = gid & 63;
        int n = (gid >> 6) & 127;
        int b = (gid >> 13) & 31;
        int k = gid >> 18;
        float s = 0.f, r = 0.f;
        const float* w1s = W1 + (k*32)*64 + c;
        const float* w1r = W1 + (k*32 + 16)*64 + c;
        const float* xp  = inp + (b*NIN)*N_ + n;    // inputs[b][f][n]
        #pragma unroll
        for (int f = 0; f < 16; ++f) {
            float xv = xp[f*N_];
            s += xv * w1s[f*64];
            r += xv * w1r[f*64];
        }
        r += b1[k*64 + c];
        Sh[gid] = (_Float16)s;
        Rh[gid] = (_Float16)r;
    } else if (bid < 4160) {
        // B-fragment: lane holds B[kk=q*8+i][n=lane&15]; idx (k,ks,nt,lane,i)
        int t = (bid - 4096)*256 + tid;     // i:3 | lane:6 | nt:2 | ks:1 | k:2
        int i    = t & 7;
        int lane = (t >> 3) & 63;
        int nt   = (t >> 9) & 3;
        int ks   = (t >> 11) & 1;
        int k    = t >> 12;
        int c = ks*32 + (lane >> 4)*8 + i;
        int o = nt*16 + (lane & 15);
        w2h[t] = (_Float16)W2[(k*64 + c)*64 + o];
    } else {
        // rtp[k][b][r][j] = rt[b][r*127+j][k], j in [0,128) padded with 0
        int t = (bid - 4160)*256 + tid;     // j:7 | r:7 | b:5 | k:2
        int j = t & 127;
        int r = (t >> 7) & 127;
        int b = (t >> 14) & 31;
        int k = t >> 19;
        float v = 0.f;
        if (j < 127) v = rt[(b*E_ + r*127 + j)*4 + k];
        rtp[t] = v;
    }
}

// ---------------------------------------------------------------------------
// Edge MLP (fp16 MFMA) + receiver aggregation + node MLP, fused.
// One block per (b, r); wave k handles edge type k over 127 edges (pad to 128).
// ---------------------------------------------------------------------------
__global__ __launch_bounds__(256) void edge_node(
    const _Float16* __restrict__ Sh, const _Float16* __restrict__ Rh,
    const _Float16* __restrict__ w2h, const float* __restrict__ rtp,
    const float* __restrict__ inp, const float* __restrict__ b2,
    const float* __restrict__ Wo1, const float* __restrict__ bo1,
    const float* __restrict__ Wo2, const float* __restrict__ bo2,
    const float* __restrict__ Wo3, const float* __restrict__ bo3,
    float* __restrict__ out)
{
    __shared__ float aggK[4*64];
    __shared__ float aug[80];
    __shared__ float psum[4][64];
    __shared__ float h1s[64];
    __shared__ float h2s[64];

    const int tid  = threadIdx.x;
    const int r    = blockIdx.x & 127;
    const int b    = blockIdx.x >> 7;
    const int k    = tid >> 6;      // wave id = edge type
    const int lane = tid & 63;
    const int col  = lane & 15;
    const int q    = lane >> 4;

    // stage x[b][r][:] for node MLP (aug[0..15])
    if (tid < 16) aug[tid] = inp[(b*NIN + tid)*N_ + r];

    // W2 B-operand fragments [ks][nt] (reused over all M-tiles)
    const h8* w2v = (const h8*)w2h;
    h8 w2f[2][4];
    #pragma unroll
    for (int ks = 0; ks < 2; ++ks)
        #pragma unroll
        for (int nt = 0; nt < 4; ++nt)
            w2f[ks][nt] = w2v[((k*2 + ks)*4 + nt)*64 + lane];

    // Receiver-side R row, kept in fp16 (packed math)
    const h8* Sv = (const h8*)Sh;
    const h8* Rv = (const h8*)Rh;
    const int rowR = ((k*B_ + b)*N_ + r) * 8;   // h8 units (row = 8 vecs)
    h8 rf0 = Rv[rowR + q];
    h8 rf1 = Rv[rowR + 4 + q];

    // b2 folded into accumulator init: C col = lane&15 for all 4 regs
    f4 b2i[4];
    #pragma unroll
    for (int nt = 0; nt < 4; ++nt) {
        float v = b2[k*64 + nt*16 + col];
        b2i[nt][0] = v; b2i[nt][1] = v; b2i[nt][2] = v; b2i[nt][3] = v;
    }

    float aggacc[4] = {0.f, 0.f, 0.f, 0.f};
    const int rowSbase = (k*B_ + b)*N_*8;
    const float* rtrow = rtp + ((k*B_ + b)*N_ + r)*128;
    const h8 zero8 = {0,0,0,0,0,0,0,0};

    #pragma unroll
    for (int mt = 0; mt < 8; ++mt) {
        // A fragment rows: h1 = relu(S[sender] + R[recv]), packed fp16
        int j = mt*16 + col;                 // A row = lane&15
        int s = j + (j >= r ? 1 : 0);        // analytic one-hot decode
        if (s > 127) s = 127;                // pad row, masked via rtp=0
        h8 a0 = Sv[rowSbase + s*8 + q]     + rf0;
        h8 a1 = Sv[rowSbase + s*8 + 4 + q] + rf1;
        a0 = __builtin_elementwise_max(a0, zero8);
        a1 = __builtin_elementwise_max(a1, zero8);

        f4 rtv = *(const f4*)(rtrow + mt*16 + q*4);   // rows q*4..q*4+3

        #pragma unroll
        for (int nt = 0; nt < 4; ++nt) {
            f4 acc = __builtin_amdgcn_mfma_f32_16x16x32_f16(a0, w2f[0][nt], b2i[nt], 0, 0, 0);
            acc     = __builtin_amdgcn_mfma_f32_16x16x32_f16(a1, w2f[1][nt], acc,    0, 0, 0);
            // C/D: col = lane&15, row = q*4 + reg
            #pragma unroll
            for (int i = 0; i < 4; ++i)
                aggacc[nt] += rtv[i] * fmaxf(acc[i], 0.f);
        }
    }

    // cross-quad reduction (rows live in quads), then per-k agg -> LDS
    #pragma unroll
    for (int nt = 0; nt < 4; ++nt) {
        float v = aggacc[nt];
        v += __shfl_xor(v, 16, 64);
        v += __shfl_xor(v, 32, 64);
        if (lane < 16) aggK[k*64 + nt*16 + lane] = v;
    }
    __syncthreads();

    // ---- node MLP (fp32), parallel across all 256 threads ----
    if (tid < 64)
        aug[16 + tid] = aggK[tid] + aggK[64 + tid] + aggK[128 + tid] + aggK[192 + tid];
    __syncthreads();

    {   // h1 = relu(aug[80] @ Wo1 + bo1): 4 partial sums of 20
        int o = tid & 63, p = tid >> 6;
        float s = 0.f;
        #pragma unroll
        for (int i = p*20; i < p*20 + 20; ++i) s += aug[i] * Wo1[i*64 + o];
        psum[p][o] = s;
    }
    __syncthreads();
    if (tid < 64)
        h1s[tid] = fmaxf(psum[0][tid] + psum[1][tid] + psum[2][tid] + psum[3][tid] + bo1[tid], 0.f);
    __syncthreads();

    {   // h2 = relu(h1 @ Wo2 + bo2): 4 partial sums of 16
        int o = tid & 63, p = tid >> 6;
        float s = 0.f;
        #pragma unroll
        for (int i = p*16; i < p*16 + 16; ++i) s += h1s[i] * Wo2[i*64 + o];
        psum[p][o] = s;
    }
    __syncthreads();
    if (tid < 64)
        h2s[tid] = fmaxf(psum[0][tid] + psum[1][tid] + psum[2][tid] + psum[3][tid] + bo2[tid], 0.f);
    __syncthreads();

    if (tid < 64) {   // pred = h2 @ Wo3 + bo3: 4 partial sums of 16
        int o = tid & 15, p = tid >> 4;
        float s = 0.f;
        #pragma unroll
        for (int i = p*16; i < p*16 + 16; ++i) s += h2s[i] * Wo3[i*16 + o];
        psum[p][o] = s;
    }
    __syncthreads();
    if (tid < 16)
        out[(b*NIN + tid)*N_ + r] =
            psum[0][tid] + psum[1][tid] + psum[2][tid] + psum[3][tid] + bo3[tid];
}

// ---------------------------------------------------------------------------
extern "C" void kernel_launch(void* const* d_in, const int* in_sizes, int n_in,
                              void* d_out, int out_size, void* d_ws, size_t ws_size,
                              hipStream_t stream)
{
    const float* inp = (const float*)d_in[0];
    // d_in[1] = rel_rec, d_in[2] = rel_send: one-hot, decoded analytically, unused
    const float* rt  = (const float*)d_in[3];
    const float* W1  = (const float*)d_in[4];
    const float* b1  = (const float*)d_in[5];
    const float* W2  = (const float*)d_in[6];
    const float* b2  = (const float*)d_in[7];
    const float* Wo1 = (const float*)d_in[8];
    const float* bo1 = (const float*)d_in[9];
    const float* Wo2 = (const float*)d_in[10];
    const float* bo2 = (const float*)d_in[11];
    const float* Wo3 = (const float*)d_in[12];
    const float* bo3 = (const float*)d_in[13];

    // ws layout: Sh 2MB | Rh 2MB | w2h 32KB | rtp 8MB   (~12.03 MB total)
    _Float16* Sh  = (_Float16*)d_ws;
    _Float16* Rh  = Sh + (1u << 20);
    _Float16* w2h = Rh + (1u << 20);
    float*    rtp = (float*)(w2h + 16384);

    hipLaunchKernelGGL(prep, dim3(12352), dim3(256), 0, stream,
                       inp, W1, b1, W2, rt, Sh, Rh, w2h, rtp);
    hipLaunchKernelGGL(edge_node, dim3(B_*N_), dim3(256), 0, stream,
                       Sh, Rh, w2h, rtp, inp, b2,
                       Wo1, bo1, Wo2, bo2, Wo3, bo3, (float*)d_out);
}